// Round 3
// baseline (42.205 us; speedup 1.0000x reference)
//
#include <hip/hip_runtime.h>

#define SEQ 2048
#define DM  2048
// B = 2. Reference einsum 'bhql,bmhn->bhqn' does NOT contract l with m:
// out[b,q,:] = ((sum_s x[b,s,:]) @ wv^T) @ wo^T, broadcast over q.

typedef float f4 __attribute__((ext_vector_type(4)));  // native vector: OK for nontemporal builtins

// ---- K1: partial column sums of x (float4, nontemporal) ----
// grid (2, 64, 2): x-half of columns, 64 row-chunks of 32, batch.
__global__ __launch_bounds__(256)
void colsum_part(const float* __restrict__ x, float* __restrict__ P) {
    int c4 = blockIdx.x * 256 + threadIdx.x;          // float4 column 0..511
    int y  = blockIdx.y;                              // 0..63
    int b  = blockIdx.z;                              // 0..1
    const f4* p = (const f4*)(x + ((size_t)b * SEQ + (size_t)y * 32) * DM) + c4;
    f4 acc = {0.f, 0.f, 0.f, 0.f};
#pragma unroll
    for (int r = 0; r < 32; ++r) {
        f4 v = __builtin_nontemporal_load(&p[(size_t)r * (DM / 4)]);
        acc += v;
    }
    ((f4*)(P + ((size_t)b * 64 + y) * DM))[c4] = acc;
}

// ---- K2: finish column sum: xsum[b][c] = sum over 64 partials (L2-resident) ----
__global__ __launch_bounds__(256)
void colsum_final(const float* __restrict__ P, float* __restrict__ xsum) {
    int c = blockIdx.x * 256 + threadIdx.x;           // 0..2047
    int b = blockIdx.y;
    const float* p = P + (size_t)b * 64 * DM + c;
    float a = 0.f;
#pragma unroll
    for (int y = 0; y < 64; ++y) a += p[(size_t)y * DM];
    xsum[b * DM + c] = a;
}

// ---- K3/K4: dual-batch matvec o[b][n] = sum_k v[b][k] * W[n][k] ----
// One weight-row read serves both batches. grid 512 blocks, 4 rows/block.
__global__ __launch_bounds__(256)
void matvec2(const float* __restrict__ v, const float* __restrict__ W,
             float* __restrict__ o) {
    int w    = threadIdx.x >> 6;          // wave 0..3
    int lane = threadIdx.x & 63;
    int n = blockIdx.x * 4 + w;           // output row
    const f4* wr = (const f4*)(W + (size_t)n * DM);
    const f4* v0 = (const f4*)v;
    const f4* v1 = (const f4*)(v + DM);
    float a0 = 0.f, a1 = 0.f;
#pragma unroll
    for (int i = lane; i < DM / 4; i += 64) {
        f4 a = __builtin_nontemporal_load(&wr[i]);
        f4 p = v0[i];
        f4 q = v1[i];
        a0 += a.x * p.x + a.y * p.y + a.z * p.z + a.w * p.w;
        a1 += a.x * q.x + a.y * q.y + a.z * q.z + a.w * q.w;
    }
#pragma unroll
    for (int m = 32; m; m >>= 1) {
        a0 += __shfl_xor(a0, m, 64);
        a1 += __shfl_xor(a1, m, 64);
    }
    if (lane == 0) { o[n] = a0; o[DM + n] = a1; }
}

// ---- K5: broadcast r[b][:] into every q row (nontemporal stores) ----
__global__ __launch_bounds__(256)
void bcast_out(const float* __restrict__ r, float* __restrict__ out) {
    int i  = blockIdx.x * 256 + threadIdx.x;          // float4 index, 2M total
    int b  = (i >= (SEQ * DM / 4)) ? 1 : 0;
    int j4 = i & (DM / 4 - 1);
    f4 val = ((const f4*)r)[b * (DM / 4) + j4];
    __builtin_nontemporal_store(val, &((f4*)out)[i]);
}

extern "C" void kernel_launch(void* const* d_in, const int* in_sizes, int n_in,
                              void* d_out, int out_size, void* d_ws, size_t ws_size,
                              hipStream_t stream) {
    const float* x  = (const float*)d_in[0];
    const float* wv = (const float*)d_in[3];
    const float* wo = (const float*)d_in[4];
    float* out = (float*)d_out;

    float* ws   = (float*)d_ws;
    float* P    = ws;                 // 2*64*2048 floats = 1 MB
    float* xsum = P + 2 * 64 * DM;    // 2*2048
    float* sv   = xsum + 2 * DM;      // 2*2048
    float* rr   = sv + 2 * DM;        // 2*2048

    colsum_part <<<dim3(2, 64, 2), 256, 0, stream>>>(x, P);
    colsum_final<<<dim3(8, 2),     256, 0, stream>>>(P, xsum);
    matvec2     <<<dim3(DM / 4),   256, 0, stream>>>(xsum, wv, sv);
    matvec2     <<<dim3(DM / 4),   256, 0, stream>>>(sv, wo, rr);

    int n4 = 2 * SEQ * DM / 4;        // 2,097,152 -> 8192 blocks
    bcast_out   <<<dim3(n4 / 256), 256, 0, stream>>>(rr, out);
}